// Round 3
// baseline (1556.390 us; speedup 1.0000x reference)
//
#include <hip/hip_runtime.h>

// Shapes: imgs(2,16,3,224,224)[shape only], i_features(8,256,56,56) fp32,
// p_motions(2,12,2,112,112) fp32 -> N=24 frames, C=256, H=W=56, k=3.
#define NPIX 3136
#define NN   24
#define CDIM 256

typedef __attribute__((ext_vector_type(8))) short short8v;   // 8 bf16 (A/B frag)
typedef __attribute__((ext_vector_type(4))) float float4v;   // 4 fp32 (C/D frag)

static __device__ __forceinline__ unsigned short f2b(float f) {
    unsigned int u = __float_as_uint(f);
    u = (u + 0x7FFFu + ((u >> 16) & 1u)) >> 16;   // RNE
    return (unsigned short)u;
}
static __device__ __forceinline__ float b2f(unsigned short h) {
    return __uint_as_float(((unsigned int)h) << 16);
}

// ---------------- resize(112->56)*scale == avg2x2 * 0.0625 ------------------
__global__ __launch_bounds__(256) void resize_pm_kernel(
    const float* __restrict__ pmo, float* __restrict__ pm)
{
    int idx = blockIdx.x * 256 + threadIdx.x;
    if (idx >= NN * 2 * NPIX) return;
    int x = idx % 56, y = (idx / 56) % 56, nc = idx / NPIX;
    const float* src = pmo + (size_t)nc * 112 * 112 + (size_t)(2 * y) * 112 + 2 * x;
    pm[idx] = (src[0] + src[1] + src[112] + src[113]) * 0.0625f;
}

// ---------------- weight packing into A-fragment order ----------------------
// dst[ch][tap][g16][lane64][8]: co = g*16 + (lane&15), ci = ch*32+(lane>>4)*8+j
// 3x3: src fp32 (co,ci,3,3), TAPS=9
__global__ __launch_bounds__(256) void pack3_kernel(
    const float* __restrict__ w, unsigned short* __restrict__ dst)
{
    int d = blockIdx.x * 256 + threadIdx.x;
    if (d >= 8 * 9 * 16 * 64 * 8) return;
    int j = d & 7;
    int lane = (d >> 3) & 63;
    int g = (d >> 9) & 15;
    int t3 = d >> 13;
    int tap = t3 % 9, ch = t3 / 9;
    int co = g * 16 + (lane & 15);
    int ci = ch * 32 + (lane >> 4) * 8 + j;
    dst[d] = f2b(w[((size_t)co * 256 + ci) * 9 + tap]);
}
// 1x1: src fp32 dw(o,c), TAPS=1
__global__ __launch_bounds__(256) void pack1_kernel(
    const float* __restrict__ w, unsigned short* __restrict__ dst)
{
    int d = blockIdx.x * 256 + threadIdx.x;
    if (d >= 8 * 16 * 64 * 8) return;
    int j = d & 7;
    int lane = (d >> 3) & 63;
    int g = (d >> 9) & 15;
    int ch = d >> 13;
    int co = g * 16 + (lane & 15);
    int ci = ch * 32 + (lane >> 4) * 8 + j;
    dst[d] = f2b(w[(size_t)co * 256 + ci]);
}

// ---------------- ew1 conv (Cin=2, K=18) fp32 direct -> bf16 NHWC + relu ----
__global__ __launch_bounds__(256) void ew1_kernel(
    const float* __restrict__ pm, const float* __restrict__ w,   // (256,2,3,3)
    const float* __restrict__ b, unsigned short* __restrict__ out)
{
    __shared__ float sT[8][18];
    __shared__ float sW1[256 * 19];
    int n = blockIdx.y;
    int pixbase = blockIdx.x * 8;
    int t = threadIdx.x;
    if (t < 144) {
        int p = t / 18, j = t % 18;
        int ci = j / 9, tap = j % 9;
        int pix = pixbase + p;
        int y = pix / 56, x = pix % 56;
        int yy = y + tap / 3 - 1, xx = x + tap % 3 - 1;
        float v = 0.f;
        if ((unsigned)yy < 56u && (unsigned)xx < 56u)
            v = pm[((size_t)n * 2 + ci) * NPIX + yy * 56 + xx];
        sT[p][j] = v;
    }
    for (int idx = t; idx < 4608; idx += 256) {
        int co = idx / 18, j = idx % 18;
        sW1[co * 19 + j] = w[idx];
    }
    __syncthreads();
    int co = t;
    float bias = b[co];
#pragma unroll
    for (int p = 0; p < 8; p++) {
        float acc = bias;
#pragma unroll
        for (int j = 0; j < 18; j++) acc += sT[p][j] * sW1[co * 19 + j];
        acc = fmaxf(acc, 0.f);
        out[((size_t)n * NPIX + pixbase + p) * 256 + co] = f2b(acc);
    }
}

// ---------------- MFMA implicit-GEMM conv (NHWC bf16 -> NHWC bf16) ----------
// Tile: 64 cout x 256 px (16x16 spatial); 4 waves each 64co x 64px.
// A-frags read straight from pre-packed global (L1/L2-resident weights);
// LDS holds only the input halo tile -> 20.7 KB -> 4 blocks/CU.
template <int TAPS, bool RELU, bool HASB>
__global__ __launch_bounds__(256, 4) void conv_mfma(
    const unsigned short* __restrict__ in,   // (NI,3136,256) bf16
    const unsigned short* __restrict__ wp,   // [8][TAPS][16][64][8] bf16
    const float* __restrict__ bias,
    unsigned short* __restrict__ out)
{
    constexpr int HALO = (TAPS == 9) ? 1 : 0;
    constexpr int IT   = 16 + 2 * HALO;           // 18 or 16
    __shared__ unsigned short sIn[IT * IT * 32];

    const int tid  = threadIdx.x;
    const int lane = tid & 63;
    const int wv   = tid >> 6;
    const int col  = lane & 15;
    const int quad = lane >> 4;
    const int tile = blockIdx.x;
    const int gBase = blockIdx.y * 4;             // A-frag group base (co = g*16+col)
    const int n = blockIdx.z;
    const int ty0 = (tile >> 2) * 16;
    const int tx0 = (tile & 3) * 16;

    const unsigned short* inN = in + (size_t)n * NPIX * 256;

    float4v acc[4][4];
#pragma unroll
    for (int mi = 0; mi < 4; mi++)
#pragma unroll
        for (int nj = 0; nj < 4; nj++) acc[mi][nj] = (float4v){0.f, 0.f, 0.f, 0.f};

    for (int ch = 0; ch < 8; ch++) {
        const int c0 = ch * 32;
        // stage input halo tile [pix][32ci], int4 per thread, conflict-free
        for (int i = tid; i < IT * IT * 4; i += 256) {
            int ci8 = i & 3, pix = i >> 2;
            int iy = pix / IT, ix = pix % IT;
            int gy = ty0 + iy - HALO, gx = tx0 + ix - HALO;
            int4 v = {0, 0, 0, 0};
            if ((unsigned)gy < 56u && (unsigned)gx < 56u)
                v = *(const int4*)(inN + ((size_t)(gy * 56 + gx) * 256 + c0 + ci8 * 8));
            *(int4*)(sIn + pix * 32 + ci8 * 8) = v;
        }
        __syncthreads();
        const unsigned short* wch = wp + ((size_t)ch * TAPS + 0) * 16 * 512;
#pragma unroll
        for (int tap = 0; tap < TAPS; tap++) {
            const int dy = (TAPS == 9) ? tap / 3 : 0;
            const int dx = (TAPS == 9) ? tap % 3 : 0;
            const unsigned short* wt = wch + ((size_t)tap * 16 + gBase) * 512 + lane * 8;
            short8v a[4], b[4];
#pragma unroll
            for (int mi = 0; mi < 4; mi++)
                a[mi] = *(const short8v*)(wt + mi * 512);
#pragma unroll
            for (int nj = 0; nj < 4; nj++) {
                int r = wv * 4 + nj;
                b[nj] = *(const short8v*)(sIn + ((r + dy) * IT + col + dx) * 32 + quad * 8);
            }
#pragma unroll
            for (int mi = 0; mi < 4; mi++)
#pragma unroll
                for (int nj = 0; nj < 4; nj++)
                    acc[mi][nj] = __builtin_amdgcn_mfma_f32_16x16x32_bf16(
                        a[mi], b[nj], acc[mi][nj], 0, 0, 0);
        }
        __syncthreads();
    }
    // epilogue: D row = quad*4+reg (cout), col = pixel
    const int coBase = blockIdx.y * 64;
    const int x = tx0 + col;
#pragma unroll
    for (int mi = 0; mi < 4; mi++) {
        float4v bv = (float4v){0.f, 0.f, 0.f, 0.f};
        if (HASB) bv = *(const float4v*)(bias + coBase + mi * 16 + quad * 4);
#pragma unroll
        for (int nj = 0; nj < 4; nj++) {
            int y = ty0 + wv * 4 + nj;
            if (y < 56 && x < 56) {
                float v0 = acc[mi][nj][0] + bv[0];
                float v1 = acc[mi][nj][1] + bv[1];
                float v2 = acc[mi][nj][2] + bv[2];
                float v3 = acc[mi][nj][3] + bv[3];
                if (RELU) {
                    v0 = fmaxf(v0, 0.f); v1 = fmaxf(v1, 0.f);
                    v2 = fmaxf(v2, 0.f); v3 = fmaxf(v3, 0.f);
                }
                uint2 pk;
                pk.x = (unsigned)f2b(v0) | ((unsigned)f2b(v1) << 16);
                pk.y = (unsigned)f2b(v2) | ((unsigned)f2b(v3) << 16);
                *(uint2*)(out + ((size_t)n * NPIX + y * 56 + x) * 256 +
                          coBase + mi * 16 + quad * 4) = pk;
            }
        }
    }
}

// ---------------- i_features NCHW fp32 -> NHWC bf16 -------------------------
__global__ __launch_bounds__(256) void transpose_fI(
    const float* __restrict__ feat, unsigned short* __restrict__ dst)
{
    __shared__ float s[64][65];
    int fi = blockIdx.z;
    int p0 = blockIdx.x * 64;
    int c0 = blockIdx.y * 64;
    int t = threadIdx.x;
    int pl = t & 63, cq = t >> 6;
#pragma unroll
    for (int i = 0; i < 16; i++) {
        int c = cq + i * 4;
        s[pl][c] = feat[((size_t)fi * 256 + c0 + c) * NPIX + p0 + pl];
    }
    __syncthreads();
    int cl = t & 63, pq = t >> 6;
#pragma unroll
    for (int i = 0; i < 16; i++) {
        int p = pq + i * 4;
        dst[((size_t)fi * NPIX + p0 + p) * 256 + c0 + cl] = f2b(s[p][cl]);
    }
}

// ---------------- deform sampling of Z (NHWC bf16) + db ---------------------
__global__ __launch_bounds__(256) void deform_kernel(
    const unsigned short* __restrict__ Z,   // (8,3136,256) bf16
    const float* __restrict__ pm,           // (24,2,3136) fp32
    const float* __restrict__ db,
    unsigned short* __restrict__ out)       // (24,3136,256) bf16
{
    int n = blockIdx.y;
    int t = threadIdx.x;
    int pix = blockIdx.x * 8 + (t >> 5);
    int g = t & 31;                  // 8-channel group
    int fi = n / 3;
    int y = pix / 56, x = pix % 56;
    float dy = pm[((size_t)n * 2 + 0) * NPIX + pix];
    float dx = pm[((size_t)n * 2 + 1) * NPIX + pix];
    float gy = (float)y + dy, gx = (float)x + dx;
    float y0f = floorf(gy), x0f = floorf(gx);
    float ty = gy - y0f, tx = gx - x0f;
    int y0 = (int)y0f, x0 = (int)x0f, y1 = y0 + 1, x1 = x0 + 1;
    bool vy0 = (unsigned)y0 < 56u, vy1 = (unsigned)y1 < 56u;
    bool vx0 = (unsigned)x0 < 56u, vx1 = (unsigned)x1 < 56u;
    float w00 = (1.f - ty) * (1.f - tx) * (vy0 && vx0 ? 1.f : 0.f);
    float w01 = (1.f - ty) * tx * (vy0 && vx1 ? 1.f : 0.f);
    float w10 = ty * (1.f - tx) * (vy1 && vx0 ? 1.f : 0.f);
    float w11 = ty * tx * (vy1 && vx1 ? 1.f : 0.f);
    int y0c = vy0 ? y0 : 0, y1c = vy1 ? y1 : 0;
    int x0c = vx0 ? x0 : 0, x1c = vx1 ? x1 : 0;
    const unsigned short* Zf = Z + (size_t)fi * NPIX * 256 + g * 8;
    const unsigned short* p00 = Zf + (size_t)(y0c * 56 + x0c) * 256;
    const unsigned short* p01 = Zf + (size_t)(y0c * 56 + x1c) * 256;
    const unsigned short* p10 = Zf + (size_t)(y1c * 56 + x0c) * 256;
    const unsigned short* p11 = Zf + (size_t)(y1c * 56 + x1c) * 256;
    unsigned short r[8];
#pragma unroll
    for (int j = 0; j < 8; j++) {
        float v = b2f(p00[j]) * w00 + b2f(p01[j]) * w01 +
                  b2f(p10[j]) * w10 + b2f(p11[j]) * w11;
        v += db[g * 8 + j];
        r[j] = f2b(v);
    }
    *(int4*)(out + ((size_t)n * NPIX + pix) * 256 + g * 8) = *(int4*)r;
}

// ---------------- final: p2d = pf+emb -> fp32 NCHW, pooled partial ----------
__global__ __launch_bounds__(256) void final_kernel(
    const unsigned short* __restrict__ pf, const unsigned short* __restrict__ emb,
    float* __restrict__ dout, float* __restrict__ acc)
{
    __shared__ float s[64 * 135];
    int n = blockIdx.y;
    int p0 = blockIdx.x * 64;
    int t = threadIdx.x;
    float* p2d = dout + 6144 + (size_t)n * CDIM * NPIX;
    for (int cpass = 0; cpass < 2; cpass++) {
        int cb = cpass * 128;
        int g = t & 15, pq = t >> 4;
#pragma unroll
        for (int ii = 0; ii < 4; ii++) {
            int p = pq + ii * 16;
            size_t base = ((size_t)n * NPIX + p0 + p) * 256 + cb + g * 8;
            int4 a4 = *(const int4*)(pf + base);
            int4 b4 = *(const int4*)(emb + base);
            const unsigned short* au = (const unsigned short*)&a4;
            const unsigned short* bu = (const unsigned short*)&b4;
#pragma unroll
            for (int j = 0; j < 8; j++)
                s[p * 135 + g * 8 + j] = b2f(au[j]) + b2f(bu[j]);
        }
        __syncthreads();
        int p = t & 63, cw = t >> 6;
#pragma unroll
        for (int i = 0; i < 32; i++) {
            int c = cw * 32 + i;
            float v = s[p * 135 + c];
            p2d[(size_t)(cb + c) * NPIX + p0 + p] = v;
            float sum = v;
#pragma unroll
            for (int off = 32; off > 0; off >>= 1) sum += __shfl_down(sum, off, 64);
            if (p == 0) atomicAdd(acc + n * CDIM + cb + c, sum);
        }
        __syncthreads();
    }
}

__global__ __launch_bounds__(256) void pooled_scale_kernel(
    const float* __restrict__ acc, float* __restrict__ dout)
{
    int i = blockIdx.x * 256 + threadIdx.x;
    if (i < 6144) dout[i] = acc[i] * (1.f / 3136.f);
}

extern "C" void kernel_launch(void* const* d_in, const int* in_sizes, int n_in,
                              void* d_out, int out_size, void* d_ws, size_t ws_size,
                              hipStream_t stream)
{
    const float* i_features = (const float*)d_in[1];
    const float* p_motions  = (const float*)d_in[2];
    const float* dw  = (const float*)d_in[3];
    const float* db  = (const float*)d_in[4];
    const float* mw1 = (const float*)d_in[5];
    const float* mb1 = (const float*)d_in[6];
    const float* mw2 = (const float*)d_in[7];
    const float* mb2 = (const float*)d_in[8];
    const float* mw3 = (const float*)d_in[9];
    const float* mb3 = (const float*)d_in[10];
    const float* ew1 = (const float*)d_in[11];
    const float* eb1 = (const float*)d_in[12];
    const float* ew2 = (const float*)d_in[13];
    const float* eb2 = (const float*)d_in[14];
    const float* ew3 = (const float*)d_in[15];
    const float* eb3 = (const float*)d_in[16];
    const float* ew4 = (const float*)d_in[17];
    const float* eb4 = (const float*)d_in[18];
    float* out = (float*)d_out;

    // workspace layout (bytes)
    char* p = (char*)d_ws;
    float* pm = (float*)p;            p += 602112;
    float* acc = (float*)p;           p += 24576;
    unsigned short* wpE2 = (unsigned short*)p; p += 1179648;
    unsigned short* wpE3 = (unsigned short*)p; p += 1179648;
    unsigned short* wpE4 = (unsigned short*)p; p += 1179648;
    unsigned short* wpM1 = (unsigned short*)p; p += 1179648;
    unsigned short* wpM2 = (unsigned short*)p; p += 1179648;
    unsigned short* wpM3 = (unsigned short*)p; p += 1179648;
    unsigned short* wpDW = (unsigned short*)p; p += 131072;
    unsigned short* actA = (unsigned short*)p; p += 38535168;
    unsigned short* actB = (unsigned short*)p; p += 38535168;
    unsigned short* embB = (unsigned short*)p; p += 38535168;

    hipMemsetAsync(acc, 0, 6144 * sizeof(float), stream);

    resize_pm_kernel<<<(NN * 2 * NPIX + 255) / 256, 256, 0, stream>>>(p_motions, pm);

    int pk3 = (8 * 9 * 16 * 64 * 8 + 255) / 256;
    pack3_kernel<<<pk3, 256, 0, stream>>>(ew2, wpE2);
    pack3_kernel<<<pk3, 256, 0, stream>>>(ew3, wpE3);
    pack3_kernel<<<pk3, 256, 0, stream>>>(ew4, wpE4);
    pack3_kernel<<<pk3, 256, 0, stream>>>(mw1, wpM1);
    pack3_kernel<<<pk3, 256, 0, stream>>>(mw2, wpM2);
    pack3_kernel<<<pk3, 256, 0, stream>>>(mw3, wpM3);
    pack1_kernel<<<(8 * 16 * 64 * 8 + 255) / 256, 256, 0, stream>>>(dw, wpDW);

    // emb chain (bf16 NHWC)
    ew1_kernel<<<dim3(392, NN), 256, 0, stream>>>(pm, ew1, eb1, actA);
    dim3 cg24(16, 4, NN), cg8(16, 4, 8);
    conv_mfma<9, true, true><<<cg24, 256, 0, stream>>>(actA, wpE2, eb2, actB);
    conv_mfma<9, true, true><<<cg24, 256, 0, stream>>>(actB, wpE3, eb3, actA);
    conv_mfma<9, true, true><<<cg24, 256, 0, stream>>>(actA, wpE4, eb4, embB);

    // Z = dw * i_features (on the 8 unique maps), then deform-sample Z (+db)
    transpose_fI<<<dim3(49, 4, 8), 256, 0, stream>>>(i_features, actA);
    conv_mfma<1, false, false><<<cg8, 256, 0, stream>>>(actA, wpDW, nullptr, actB);
    deform_kernel<<<dim3(392, NN), 256, 0, stream>>>(actB, pm, db, actA);

    // pf chain
    conv_mfma<9, true, true><<<cg24, 256, 0, stream>>>(actA, wpM1, mb1, actB);
    conv_mfma<9, true, true><<<cg24, 256, 0, stream>>>(actB, wpM2, mb2, actA);
    conv_mfma<9, true, true><<<cg24, 256, 0, stream>>>(actA, wpM3, mb3, actB);

    // p2d + pooled
    final_kernel<<<dim3(49, NN), 256, 0, stream>>>(actB, embB, out, acc);
    pooled_scale_kernel<<<24, 256, 0, stream>>>(acc, out);
}

// Round 4
// 890.568 us; speedup vs baseline: 1.7476x; 1.7476x over previous
//
#include <hip/hip_runtime.h>

// Shapes: imgs(2,16,3,224,224)[shape only], i_features(8,256,56,56) fp32,
// p_motions(2,12,2,112,112) fp32 -> N=24 frames, C=256, H=W=56, k=3.
#define NPIX 3136
#define NN   24
#define CDIM 256

typedef __attribute__((ext_vector_type(8))) short short8v;   // 8 bf16 (A/B frag)
typedef __attribute__((ext_vector_type(4))) float float4v;   // 4 fp32 (C/D frag)

typedef __attribute__((address_space(1))) const void gvoid;
typedef __attribute__((address_space(3))) void lvoid;
static __device__ __forceinline__ void async_copy16(const void* g, void* l) {
    // lane's 16B lands at l + lane*16 (wave-uniform LDS base)
    __builtin_amdgcn_global_load_lds((gvoid*)g, (lvoid*)l, 16, 0, 0);
}

static __device__ __forceinline__ unsigned short f2b(float f) {
    unsigned int u = __float_as_uint(f);
    u = (u + 0x7FFFu + ((u >> 16) & 1u)) >> 16;   // RNE
    return (unsigned short)u;
}
static __device__ __forceinline__ float b2f(unsigned short h) {
    return __uint_as_float(((unsigned int)h) << 16);
}

// ---------------- resize(112->56)*scale == avg2x2 * 0.0625 ------------------
__global__ __launch_bounds__(256) void resize_pm_kernel(
    const float* __restrict__ pmo, float* __restrict__ pm)
{
    int idx = blockIdx.x * 256 + threadIdx.x;
    if (idx >= NN * 2 * NPIX) return;
    int x = idx % 56, y = (idx / 56) % 56, nc = idx / NPIX;
    const float* src = pmo + (size_t)nc * 112 * 112 + (size_t)(2 * y) * 112 + 2 * x;
    pm[idx] = (src[0] + src[1] + src[112] + src[113]) * 0.0625f;
}

// ---------------- weight packing, block-contiguous fragment order ------------
// 3x3: dst [cb4][ch8][tap9][g4][lane64][8]; co=cb*64+g*16+(lane&15),
//      ci=ch*32+(lane>>4)*8+j; src fp32 (co,ci,3,3)
__global__ __launch_bounds__(256) void pack3_kernel(
    const float* __restrict__ w, unsigned short* __restrict__ dst)
{
    int d = blockIdx.x * 256 + threadIdx.x;
    if (d >= 589824) return;
    int j = d & 7;
    int lane = (d >> 3) & 63;
    int g = (d >> 9) & 3;
    int e = d >> 11;
    int tap = e % 9;
    int f = e / 9;
    int ch = f & 7, cb = f >> 3;
    int co = cb * 64 + g * 16 + (lane & 15);
    int ci = ch * 32 + (lane >> 4) * 8 + j;
    dst[d] = f2b(w[((size_t)co * 256 + ci) * 9 + tap]);
}
// 1x1: dst [cb4][ch8][g4][lane64][8]; src fp32 dw(o,c)
__global__ __launch_bounds__(256) void pack1_kernel(
    const float* __restrict__ w, unsigned short* __restrict__ dst)
{
    int d = blockIdx.x * 256 + threadIdx.x;
    if (d >= 65536) return;
    int j = d & 7;
    int lane = (d >> 3) & 63;
    int g = (d >> 9) & 3;
    int ch = (d >> 11) & 7;
    int cb = d >> 14;
    int co = cb * 64 + g * 16 + (lane & 15);
    int ci = ch * 32 + (lane >> 4) * 8 + j;
    dst[d] = f2b(w[(size_t)co * 256 + ci]);
}

// ---------------- ew1 conv (Cin=2, K=18) fp32 direct -> bf16 NHWC + relu ----
__global__ __launch_bounds__(256) void ew1_kernel(
    const float* __restrict__ pm, const float* __restrict__ w,   // (256,2,3,3)
    const float* __restrict__ b, unsigned short* __restrict__ out)
{
    __shared__ float sT[8][18];
    __shared__ float sW1[256 * 19];
    int n = blockIdx.y;
    int pixbase = blockIdx.x * 8;
    int t = threadIdx.x;
    if (t < 144) {
        int p = t / 18, j = t % 18;
        int ci = j / 9, tap = j % 9;
        int pix = pixbase + p;
        int y = pix / 56, x = pix % 56;
        int yy = y + tap / 3 - 1, xx = x + tap % 3 - 1;
        float v = 0.f;
        if ((unsigned)yy < 56u && (unsigned)xx < 56u)
            v = pm[((size_t)n * 2 + ci) * NPIX + yy * 56 + xx];
        sT[p][j] = v;
    }
    for (int idx = t; idx < 4608; idx += 256) {
        int co = idx / 18, j = idx % 18;
        sW1[co * 19 + j] = w[idx];
    }
    __syncthreads();
    int co = t;
    float bias = b[co];
#pragma unroll
    for (int p = 0; p < 8; p++) {
        float acc = bias;
#pragma unroll
        for (int j = 0; j < 18; j++) acc += sT[p][j] * sW1[co * 19 + j];
        acc = fmaxf(acc, 0.f);
        out[((size_t)n * NPIX + pixbase + p) * 256 + co] = f2b(acc);
    }
}

// ---------------- MFMA implicit-GEMM conv (NHWC bf16 -> NHWC bf16) ----------
// Tile: 64 cout x 448 px (28x16 spatial); 4 waves each 64co x 112px (4x7 acc).
// sIn layout [q4][pixTile][8] -> B-frag quarter-waves read 256B contiguous
// (conflict-free). Weights pre-packed in fragment order -> contiguous staging
// + contiguous A-frag reads. Both staged via async global_load_lds (16B).
template <int TAPS, bool RELU, bool HASB>
__global__ __launch_bounds__(256, 2) void conv_mfma(
    const unsigned short* __restrict__ in,   // (NI,3136,256) bf16
    const unsigned short* __restrict__ wp,   // [4][8][TAPS][4][64][8] bf16
    const float* __restrict__ bias,
    unsigned short* __restrict__ out)
{
    constexpr int HALO = (TAPS == 9) ? 1 : 0;
    constexpr int IY = 28 + 2 * HALO;             // 30 / 28
    constexpr int IX = 16 + 2 * HALO;             // 18 / 16
    constexpr int NPT = IY * IX;                  // 540 / 448
    constexpr int SIN_ITERS = (4 * NPT + 63) / 64;  // 34 / 28 (1KB wave-iters)
    constexpr int W_ITERS = TAPS * 4;             // 36 / 4
    constexpr int MAXK = (SIN_ITERS + 3) / 4;     // 9 / 7

    __shared__ unsigned short sIn[SIN_ITERS * 512];
    __shared__ unsigned short sW[W_ITERS * 512];

    const int tid = threadIdx.x;
    const int lane = tid & 63;
    const int wv = tid >> 6;
    const int col = lane & 15;
    const int quad = lane >> 4;
    const int tile = blockIdx.x;       // 0..7: ty = tile>>2 (2), tx = tile&3 (4)
    const int cb = blockIdx.y;         // 64-cout block
    const int n = blockIdx.z;
    const int ty0 = (tile >> 2) * 28;
    const int tx0 = (tile & 3) * 16;

    const unsigned short* inN = in + (size_t)n * NPIX * 256;
    const unsigned short* wcb = wp + (size_t)cb * 8 * W_ITERS * 512;

    // per-thread sIn staging offsets (elements); -1 = skip (halo/pad)
    int soff[MAXK];
#pragma unroll
    for (int k = 0; k < MAXK; k++) {
        int it = wv + k * 4;
        soff[k] = -1;
        if (it < SIN_ITERS) {
            int u = it * 64 + lane;
            if (u < 4 * NPT) {
                int q = u / NPT, pix = u - q * NPT;
                int iy = pix / IX, ix = pix - iy * IX;
                int gy = ty0 + iy - HALO, gx = tx0 + ix - HALO;
                if ((unsigned)gy < 56u && (unsigned)gx < 56u)
                    soff[k] = (gy * 56 + gx) * 256 + q * 8;
            }
        }
    }
    // prezero sIn: halo/pad slots stay 0 (masked lanes never overwrite them)
    for (int i = tid * 8; i < SIN_ITERS * 512; i += 256 * 8)
        *(int4*)(sIn + i) = (int4){0, 0, 0, 0};

    float4v acc[4][7];
#pragma unroll
    for (int mi = 0; mi < 4; mi++)
#pragma unroll
        for (int nj = 0; nj < 7; nj++) acc[mi][nj] = (float4v){0.f, 0.f, 0.f, 0.f};

    for (int ch = 0; ch < 8; ch++) {
        __syncthreads();   // prev compute done (first pass: prezero visible)
        // stage weights: contiguous 1KB per wave-iter
        const unsigned short* wchunk = wcb + (size_t)ch * W_ITERS * 512;
#pragma unroll
        for (int it = wv; it < W_ITERS; it += 4)
            async_copy16(wchunk + it * 512 + lane * 8, sW + it * 512);
        // stage input tile
#pragma unroll
        for (int k = 0; k < MAXK; k++) {
            int it = wv + k * 4;
            if (it < SIN_ITERS && soff[k] >= 0)
                async_copy16(inN + soff[k] + ch * 32, sIn + it * 512);
        }
        __syncthreads();   // vmcnt drain + visibility
#pragma unroll
        for (int tap = 0; tap < TAPS; tap++) {
            const int dy = (TAPS == 9) ? tap / 3 : 0;
            const int dx = (TAPS == 9) ? tap % 3 : 0;
            short8v a[4], b[7];
#pragma unroll
            for (int mi = 0; mi < 4; mi++)
                a[mi] = *(const short8v*)(sW + ((tap * 4 + mi) * 64 + lane) * 8);
#pragma unroll
            for (int nj = 0; nj < 7; nj++) {
                int pix = (wv * 7 + nj + dy) * IX + col + dx;
                b[nj] = *(const short8v*)(sIn + (quad * NPT + pix) * 8);
            }
#pragma unroll
            for (int mi = 0; mi < 4; mi++)
#pragma unroll
                for (int nj = 0; nj < 7; nj++)
                    acc[mi][nj] = __builtin_amdgcn_mfma_f32_16x16x32_bf16(
                        a[mi], b[nj], acc[mi][nj], 0, 0, 0);
        }
    }

    // epilogue: D row = quad*4+reg (cout), col = pixel-x
    const int x = tx0 + col;
    const int coBase = cb * 64;
#pragma unroll
    for (int mi = 0; mi < 4; mi++) {
        float4v bv = (float4v){0.f, 0.f, 0.f, 0.f};
        if (HASB) bv = *(const float4v*)(bias + coBase + mi * 16 + quad * 4);
#pragma unroll
        for (int nj = 0; nj < 7; nj++) {
            int y = ty0 + wv * 7 + nj;   // always < 56 (28*2 exact)
            if (x < 56) {
                float v0 = acc[mi][nj][0] + bv[0];
                float v1 = acc[mi][nj][1] + bv[1];
                float v2 = acc[mi][nj][2] + bv[2];
                float v3 = acc[mi][nj][3] + bv[3];
                if (RELU) {
                    v0 = fmaxf(v0, 0.f); v1 = fmaxf(v1, 0.f);
                    v2 = fmaxf(v2, 0.f); v3 = fmaxf(v3, 0.f);
                }
                uint2 pk;
                pk.x = (unsigned)f2b(v0) | ((unsigned)f2b(v1) << 16);
                pk.y = (unsigned)f2b(v2) | ((unsigned)f2b(v3) << 16);
                *(uint2*)(out + ((size_t)n * NPIX + y * 56 + x) * 256 +
                          coBase + mi * 16 + quad * 4) = pk;
            }
        }
    }
}

// ---------------- i_features NCHW fp32 -> NHWC bf16 -------------------------
__global__ __launch_bounds__(256) void transpose_fI(
    const float* __restrict__ feat, unsigned short* __restrict__ dst)
{
    __shared__ float s[64][65];
    int fi = blockIdx.z;
    int p0 = blockIdx.x * 64;
    int c0 = blockIdx.y * 64;
    int t = threadIdx.x;
    int pl = t & 63, cq = t >> 6;
#pragma unroll
    for (int i = 0; i < 16; i++) {
        int c = cq + i * 4;
        s[pl][c] = feat[((size_t)fi * 256 + c0 + c) * NPIX + p0 + pl];
    }
    __syncthreads();
    int cl = t & 63, pq = t >> 6;
#pragma unroll
    for (int i = 0; i < 16; i++) {
        int p = pq + i * 4;
        dst[((size_t)fi * NPIX + p0 + p) * 256 + c0 + cl] = f2b(s[p][cl]);
    }
}

// ---------------- deform sampling of Z (NHWC bf16) + db ---------------------
__global__ __launch_bounds__(256) void deform_kernel(
    const unsigned short* __restrict__ Z,   // (8,3136,256) bf16
    const float* __restrict__ pm,           // (24,2,3136) fp32
    const float* __restrict__ db,
    unsigned short* __restrict__ out)       // (24,3136,256) bf16
{
    int n = blockIdx.y;
    int t = threadIdx.x;
    int pix = blockIdx.x * 8 + (t >> 5);
    int g = t & 31;                  // 8-channel group
    int fi = n / 3;
    int y = pix / 56, x = pix % 56;
    float dy = pm[((size_t)n * 2 + 0) * NPIX + pix];
    float dx = pm[((size_t)n * 2 + 1) * NPIX + pix];
    float gy = (float)y + dy, gx = (float)x + dx;
    float y0f = floorf(gy), x0f = floorf(gx);
    float ty = gy - y0f, tx = gx - x0f;
    int y0 = (int)y0f, x0 = (int)x0f, y1 = y0 + 1, x1 = x0 + 1;
    bool vy0 = (unsigned)y0 < 56u, vy1 = (unsigned)y1 < 56u;
    bool vx0 = (unsigned)x0 < 56u, vx1 = (unsigned)x1 < 56u;
    float w00 = (1.f - ty) * (1.f - tx) * (vy0 && vx0 ? 1.f : 0.f);
    float w01 = (1.f - ty) * tx * (vy0 && vx1 ? 1.f : 0.f);
    float w10 = ty * (1.f - tx) * (vy1 && vx0 ? 1.f : 0.f);
    float w11 = ty * tx * (vy1 && vx1 ? 1.f : 0.f);
    int y0c = vy0 ? y0 : 0, y1c = vy1 ? y1 : 0;
    int x0c = vx0 ? x0 : 0, x1c = vx1 ? x1 : 0;
    const unsigned short* Zf = Z + (size_t)fi * NPIX * 256 + g * 8;
    const unsigned short* p00 = Zf + (size_t)(y0c * 56 + x0c) * 256;
    const unsigned short* p01 = Zf + (size_t)(y0c * 56 + x1c) * 256;
    const unsigned short* p10 = Zf + (size_t)(y1c * 56 + x0c) * 256;
    const unsigned short* p11 = Zf + (size_t)(y1c * 56 + x1c) * 256;
    unsigned short r[8];
#pragma unroll
    for (int j = 0; j < 8; j++) {
        float v = b2f(p00[j]) * w00 + b2f(p01[j]) * w01 +
                  b2f(p10[j]) * w10 + b2f(p11[j]) * w11;
        v += db[g * 8 + j];
        r[j] = f2b(v);
    }
    *(int4*)(out + ((size_t)n * NPIX + pix) * 256 + g * 8) = *(int4*)r;
}

// ---------------- final: p2d = pf+emb -> fp32 NCHW, pooled partial ----------
__global__ __launch_bounds__(256) void final_kernel(
    const unsigned short* __restrict__ pf, const unsigned short* __restrict__ emb,
    float* __restrict__ dout, float* __restrict__ acc)
{
    __shared__ float s[64 * 135];
    int n = blockIdx.y;
    int p0 = blockIdx.x * 64;
    int t = threadIdx.x;
    float* p2d = dout + 6144 + (size_t)n * CDIM * NPIX;
    for (int cpass = 0; cpass < 2; cpass++) {
        int cb = cpass * 128;
        int g = t & 15, pq = t >> 4;
#pragma unroll
        for (int ii = 0; ii < 4; ii++) {
            int p = pq + ii * 16;
            size_t base = ((size_t)n * NPIX + p0 + p) * 256 + cb + g * 8;
            int4 a4 = *(const int4*)(pf + base);
            int4 b4 = *(const int4*)(emb + base);
            const unsigned short* au = (const unsigned short*)&a4;
            const unsigned short* bu = (const unsigned short*)&b4;
#pragma unroll
            for (int j = 0; j < 8; j++)
                s[p * 135 + g * 8 + j] = b2f(au[j]) + b2f(bu[j]);
        }
        __syncthreads();
        int p = t & 63, cw = t >> 6;
#pragma unroll
        for (int i = 0; i < 32; i++) {
            int c = cw * 32 + i;
            float v = s[p * 135 + c];
            p2d[(size_t)(cb + c) * NPIX + p0 + p] = v;
            float sum = v;
#pragma unroll
            for (int off = 32; off > 0; off >>= 1) sum += __shfl_down(sum, off, 64);
            if (p == 0) atomicAdd(acc + n * CDIM + cb + c, sum);
        }
        __syncthreads();
    }
}

__global__ __launch_bounds__(256) void pooled_scale_kernel(
    const float* __restrict__ acc, float* __restrict__ dout)
{
    int i = blockIdx.x * 256 + threadIdx.x;
    if (i < 6144) dout[i] = acc[i] * (1.f / 3136.f);
}

extern "C" void kernel_launch(void* const* d_in, const int* in_sizes, int n_in,
                              void* d_out, int out_size, void* d_ws, size_t ws_size,
                              hipStream_t stream)
{
    const float* i_features = (const float*)d_in[1];
    const float* p_motions  = (const float*)d_in[2];
    const float* dw  = (const float*)d_in[3];
    const float* db  = (const float*)d_in[4];
    const float* mw1 = (const float*)d_in[5];
    const float* mb1 = (const float*)d_in[6];
    const float* mw2 = (const float*)d_in[7];
    const float* mb2 = (const float*)d_in[8];
    const float* mw3 = (const float*)d_in[9];
    const float* mb3 = (const float*)d_in[10];
    const float* ew1 = (const float*)d_in[11];
    const float* eb1 = (const float*)d_in[12];
    const float* ew2 = (const float*)d_in[13];
    const float* eb2 = (const float*)d_in[14];
    const float* ew3 = (const float*)d_in[15];
    const float* eb3 = (const float*)d_in[16];
    const float* ew4 = (const float*)d_in[17];
    const float* eb4 = (const float*)d_in[18];
    float* out = (float*)d_out;

    // workspace layout (bytes)
    char* p = (char*)d_ws;
    float* pm = (float*)p;            p += 602112;
    float* acc = (float*)p;           p += 24576;
    unsigned short* wpE2 = (unsigned short*)p; p += 1179648;
    unsigned short* wpE3 = (unsigned short*)p; p += 1179648;
    unsigned short* wpE4 = (unsigned short*)p; p += 1179648;
    unsigned short* wpM1 = (unsigned short*)p; p += 1179648;
    unsigned short* wpM2 = (unsigned short*)p; p += 1179648;
    unsigned short* wpM3 = (unsigned short*)p; p += 1179648;
    unsigned short* wpDW = (unsigned short*)p; p += 131072;
    unsigned short* actA = (unsigned short*)p; p += 38535168;
    unsigned short* actB = (unsigned short*)p; p += 38535168;
    unsigned short* embB = (unsigned short*)p; p += 38535168;

    hipMemsetAsync(acc, 0, 6144 * sizeof(float), stream);

    resize_pm_kernel<<<(NN * 2 * NPIX + 255) / 256, 256, 0, stream>>>(p_motions, pm);

    int pk3 = (589824 + 255) / 256;
    pack3_kernel<<<pk3, 256, 0, stream>>>(ew2, wpE2);
    pack3_kernel<<<pk3, 256, 0, stream>>>(ew3, wpE3);
    pack3_kernel<<<pk3, 256, 0, stream>>>(ew4, wpE4);
    pack3_kernel<<<pk3, 256, 0, stream>>>(mw1, wpM1);
    pack3_kernel<<<pk3, 256, 0, stream>>>(mw2, wpM2);
    pack3_kernel<<<pk3, 256, 0, stream>>>(mw3, wpM3);
    pack1_kernel<<<(65536 + 255) / 256, 256, 0, stream>>>(dw, wpDW);

    // emb chain (bf16 NHWC)
    ew1_kernel<<<dim3(392, NN), 256, 0, stream>>>(pm, ew1, eb1, actA);
    dim3 cg24(8, 4, NN), cg8(8, 4, 8);
    conv_mfma<9, true, true><<<cg24, 256, 0, stream>>>(actA, wpE2, eb2, actB);
    conv_mfma<9, true, true><<<cg24, 256, 0, stream>>>(actB, wpE3, eb3, actA);
    conv_mfma<9, true, true><<<cg24, 256, 0, stream>>>(actA, wpE4, eb4, embB);

    // Z = dw * i_features (on the 8 unique maps), then deform-sample Z (+db)
    transpose_fI<<<dim3(49, 4, 8), 256, 0, stream>>>(i_features, actA);
    conv_mfma<1, false, false><<<cg8, 256, 0, stream>>>(actA, wpDW, nullptr, actB);
    deform_kernel<<<dim3(392, NN), 256, 0, stream>>>(actB, pm, db, actA);

    // pf chain
    conv_mfma<9, true, true><<<cg24, 256, 0, stream>>>(actA, wpM1, mb1, actB);
    conv_mfma<9, true, true><<<cg24, 256, 0, stream>>>(actB, wpM2, mb2, actA);
    conv_mfma<9, true, true><<<cg24, 256, 0, stream>>>(actA, wpM3, mb3, actB);

    // p2d + pooled
    final_kernel<<<dim3(49, NN), 256, 0, stream>>>(actB, embB, out, acc);
    pooled_scale_kernel<<<24, 256, 0, stream>>>(acc, out);
}

// Round 5
// 842.088 us; speedup vs baseline: 1.8483x; 1.0576x over previous
//
#include <hip/hip_runtime.h>

// Shapes: imgs(2,16,3,224,224)[shape only], i_features(8,256,56,56) fp32,
// p_motions(2,12,2,112,112) fp32 -> N=24 frames, C=256, H=W=56, k=3.
#define NPIX 3136
#define NN   24
#define CDIM 256

typedef __attribute__((ext_vector_type(8))) short short8v;   // 8 bf16 (A/B frag)
typedef __attribute__((ext_vector_type(4))) float float4v;   // 4 fp32 (C/D frag)

typedef __attribute__((address_space(1))) const void gvoid;
typedef __attribute__((address_space(3))) void lvoid;
static __device__ __forceinline__ void async_copy16(const void* g, void* l) {
    // lane's 16B lands at l + lane*16 (wave-uniform LDS base)
    __builtin_amdgcn_global_load_lds((gvoid*)g, (lvoid*)l, 16, 0, 0);
}

static __device__ __forceinline__ unsigned short f2b(float f) {
    unsigned int u = __float_as_uint(f);
    u = (u + 0x7FFFu + ((u >> 16) & 1u)) >> 16;   // RNE
    return (unsigned short)u;
}
static __device__ __forceinline__ float b2f(unsigned short h) {
    return __uint_as_float(((unsigned int)h) << 16);
}

// ---------------- resize(112->56)*scale == avg2x2 * 0.0625 ------------------
__global__ __launch_bounds__(256) void resize_pm_kernel(
    const float* __restrict__ pmo, float* __restrict__ pm)
{
    int idx = blockIdx.x * 256 + threadIdx.x;
    if (idx >= NN * 2 * NPIX) return;
    int x = idx % 56, y = (idx / 56) % 56, nc = idx / NPIX;
    const float* src = pmo + (size_t)nc * 112 * 112 + (size_t)(2 * y) * 112 + 2 * x;
    pm[idx] = (src[0] + src[1] + src[112] + src[113]) * 0.0625f;
}

// ---------------- merged weight packing (6x 3x3 + 1x 1x1) -------------------
// 3x3: dst [cb4][ch8][tap9][g4][lane64][8]; co=cb*64+g*16+(lane&15),
//      ci=ch*32+(lane>>4)*8+j. 1x1 same without tap. dsts contiguous in ws.
__global__ __launch_bounds__(256) void pack_all_kernel(
    const float* __restrict__ s0, const float* __restrict__ s1,
    const float* __restrict__ s2, const float* __restrict__ s3,
    const float* __restrict__ s4, const float* __restrict__ s5,
    const float* __restrict__ sdw, unsigned short* __restrict__ dstbase)
{
    int bx = blockIdx.x;
    if (bx < 6 * 2304) {
        int wi = bx / 2304;
        int d = (bx % 2304) * 256 + threadIdx.x;
        const float* w = (wi == 0) ? s0 : (wi == 1) ? s1 : (wi == 2) ? s2
                       : (wi == 3) ? s3 : (wi == 4) ? s4 : s5;
        int j = d & 7;
        int lane = (d >> 3) & 63;
        int g = (d >> 9) & 3;
        int e = d >> 11;
        int tap = e % 9;
        int f = e / 9;
        int ch = f & 7, cb = f >> 3;
        int co = cb * 64 + g * 16 + (lane & 15);
        int ci = ch * 32 + (lane >> 4) * 8 + j;
        dstbase[(size_t)wi * 589824 + d] = f2b(w[((size_t)co * 256 + ci) * 9 + tap]);
    } else {
        int d = (bx - 6 * 2304) * 256 + threadIdx.x;
        int j = d & 7;
        int lane = (d >> 3) & 63;
        int g = (d >> 9) & 3;
        int ch = (d >> 11) & 7;
        int cb = d >> 14;
        int co = cb * 64 + g * 16 + (lane & 15);
        int ci = ch * 32 + (lane >> 4) * 8 + j;
        dstbase[(size_t)6 * 589824 + d] = f2b(sdw[(size_t)co * 256 + ci]);
    }
}

// ---------------- ew1 conv (Cin=2, K=18) fp32 direct -> bf16 NHWC + relu ----
__global__ __launch_bounds__(256) void ew1_kernel(
    const float* __restrict__ pm, const float* __restrict__ w,   // (256,2,3,3)
    const float* __restrict__ b, unsigned short* __restrict__ out)
{
    __shared__ float sT[8][18];
    __shared__ float sW1[256 * 19];
    int n = blockIdx.y;
    int pixbase = blockIdx.x * 8;
    int t = threadIdx.x;
    if (t < 144) {
        int p = t / 18, j = t % 18;
        int ci = j / 9, tap = j % 9;
        int pix = pixbase + p;
        int y = pix / 56, x = pix % 56;
        int yy = y + tap / 3 - 1, xx = x + tap % 3 - 1;
        float v = 0.f;
        if ((unsigned)yy < 56u && (unsigned)xx < 56u)
            v = pm[((size_t)n * 2 + ci) * NPIX + yy * 56 + xx];
        sT[p][j] = v;
    }
    for (int idx = t; idx < 4608; idx += 256) {
        int co = idx / 18, j = idx % 18;
        sW1[co * 19 + j] = w[idx];
    }
    __syncthreads();
    int co = t;
    float bias = b[co];
#pragma unroll
    for (int p = 0; p < 8; p++) {
        float acc = bias;
#pragma unroll
        for (int j = 0; j < 18; j++) acc += sT[p][j] * sW1[co * 19 + j];
        acc = fmaxf(acc, 0.f);
        out[((size_t)n * NPIX + pixbase + p) * 256 + co] = f2b(acc);
    }
}

// ---------------- MFMA implicit-GEMM conv (NHWC bf16 -> NHWC bf16) ----------
// Row-flattened tile: 64 cout x 448 px = 8 FULL rows (no x-waste, exact 7x
// grid cover). 4 waves each 64co x 112px (4x7 acc). 3x3: LDS input
// [10 rows][58 pos][32 ci] zero-padded borders; 1x1: [448 px][32 ci].
// Weights pre-packed in fragment order; both staged via global_load_lds(16B).
template <int TAPS, bool RELU, bool HASB>
__global__ __launch_bounds__(256, 2) void conv_mfma(
    const unsigned short* __restrict__ in,   // (NI,3136,256) bf16
    const unsigned short* __restrict__ wp,   // [4][8][TAPS][4][64][8] bf16
    const float* __restrict__ bias,
    unsigned short* __restrict__ out)
{
    constexpr int W_ITERS = TAPS * 4;                       // 36 / 4
    constexpr int SIN_SHORTS = (TAPS == 9) ? 10 * 58 * 32 : 448 * 32;

    __shared__ unsigned short sIn[SIN_SHORTS];
    __shared__ unsigned short sW[W_ITERS * 512];

    const int tid = threadIdx.x;
    const int lane = tid & 63;
    const int wv = tid >> 6;
    const int col = lane & 15;
    const int quad = lane >> 4;
    const int r0 = blockIdx.x * 8;     // row base (7 tiles x 8 rows = 56)
    const int cb = blockIdx.y;         // 64-cout block
    const int n = blockIdx.z;

    const unsigned short* inN = in + (size_t)n * NPIX * 256;
    const unsigned short* wcb = wp + (size_t)cb * 8 * W_ITERS * 512;

    // per-lane B-frag row offsets (y*58 + x for 3x3; flat px for 1x1)
    int rowoff[7];
#pragma unroll
    for (int nj = 0; nj < 7; nj++) {
        int pxl = wv * 112 + nj * 16 + col;
        if (TAPS == 9) {
            int yl = pxl / 56;
            rowoff[nj] = yl * 58 + (pxl - yl * 56);
        } else {
            rowoff[nj] = pxl;
        }
    }
    const int qoff = quad * 8;
    // per-lane global staging offset within a 16px x 32ci slab
    const int laneSrc = (lane >> 2) * 256 + (lane & 3) * 8;

    if (TAPS == 9) {
        // prezero: x-border pads + out-of-image halo rows stay 0 all chunks
        for (int i = tid * 8; i < SIN_SHORTS; i += 2048)
            *(int4*)(sIn + i) = (int4){0, 0, 0, 0};
    }

    float4v acc[4][7];
#pragma unroll
    for (int mi = 0; mi < 4; mi++)
#pragma unroll
        for (int nj = 0; nj < 7; nj++) acc[mi][nj] = (float4v){0.f, 0.f, 0.f, 0.f};

    for (int ch = 0; ch < 8; ch++) {
        const int c0 = ch * 32;
        __syncthreads();   // prev compute done (first pass: prezero visible)
        // stage weights: contiguous 1KB per wave-iter
        const unsigned short* wchunk = wcb + (size_t)ch * W_ITERS * 512;
#pragma unroll
        for (int it = wv; it < W_ITERS; it += 4)
            async_copy16(wchunk + it * 512 + lane * 8, sW + it * 512);
        // stage input
        if (TAPS == 9) {
#pragma unroll
            for (int ry = 0; ry < 10; ry++) {
                int k = (wv - ry) & 3;          // all (ry,k) covered, balanced
                int gy = r0 + ry - 1;
                if ((unsigned)gy < 56u && (k < 3 || lane < 32))
                    async_copy16(inN + (size_t)gy * 14336 + k * 4096 + c0 + laneSrc,
                                 sIn + ry * 1856 + 32 + k * 512);
            }
        } else {
#pragma unroll
            for (int k = 0; k < 7; k++) {
                int it = wv + k * 4;
                async_copy16(inN + (size_t)r0 * 14336 + it * 4096 + c0 + laneSrc,
                             sIn + it * 512);
            }
        }
        __syncthreads();   // drain + visibility
#pragma unroll
        for (int tap = 0; tap < TAPS; tap++) {
            const int coff = (TAPS == 9) ? ((tap / 3) * 58 + (tap % 3)) * 32 : 0;
            short8v a[4], b[7];
#pragma unroll
            for (int mi = 0; mi < 4; mi++)
                a[mi] = *(const short8v*)(sW + ((tap * 4 + mi) * 64 + lane) * 8);
#pragma unroll
            for (int nj = 0; nj < 7; nj++)
                b[nj] = *(const short8v*)(sIn + rowoff[nj] * 32 + coff + qoff);
#pragma unroll
            for (int mi = 0; mi < 4; mi++)
#pragma unroll
                for (int nj = 0; nj < 7; nj++)
                    acc[mi][nj] = __builtin_amdgcn_mfma_f32_16x16x32_bf16(
                        a[mi], b[nj], acc[mi][nj], 0, 0, 0);
        }
    }

    // epilogue: D row = quad*4+reg (cout), col = pixel; no masks (exact tiles)
    unsigned short* outT = out + ((size_t)n * NPIX + r0 * 56 + wv * 112) * 256 + cb * 64;
#pragma unroll
    for (int mi = 0; mi < 4; mi++) {
        float4v bv = (float4v){0.f, 0.f, 0.f, 0.f};
        if (HASB) bv = *(const float4v*)(bias + cb * 64 + mi * 16 + quad * 4);
#pragma unroll
        for (int nj = 0; nj < 7; nj++) {
            float v0 = acc[mi][nj][0] + bv[0];
            float v1 = acc[mi][nj][1] + bv[1];
            float v2 = acc[mi][nj][2] + bv[2];
            float v3 = acc[mi][nj][3] + bv[3];
            if (RELU) {
                v0 = fmaxf(v0, 0.f); v1 = fmaxf(v1, 0.f);
                v2 = fmaxf(v2, 0.f); v3 = fmaxf(v3, 0.f);
            }
            uint2 pk;
            pk.x = (unsigned)f2b(v0) | ((unsigned)f2b(v1) << 16);
            pk.y = (unsigned)f2b(v2) | ((unsigned)f2b(v3) << 16);
            *(uint2*)(outT + ((size_t)(nj * 16 + col)) * 256 + mi * 16 + quad * 4) = pk;
        }
    }
}

// ---------------- i_features NCHW fp32 -> NHWC bf16 -------------------------
__global__ __launch_bounds__(256) void transpose_fI(
    const float* __restrict__ feat, unsigned short* __restrict__ dst)
{
    __shared__ float s[64][65];
    int fi = blockIdx.z;
    int p0 = blockIdx.x * 64;
    int c0 = blockIdx.y * 64;
    int t = threadIdx.x;
    int pl = t & 63, cq = t >> 6;
#pragma unroll
    for (int i = 0; i < 16; i++) {
        int c = cq + i * 4;
        s[pl][c] = feat[((size_t)fi * 256 + c0 + c) * NPIX + p0 + pl];
    }
    __syncthreads();
    int cl = t & 63, pq = t >> 6;
#pragma unroll
    for (int i = 0; i < 16; i++) {
        int p = pq + i * 4;
        dst[((size_t)fi * NPIX + p0 + p) * 256 + c0 + cl] = f2b(s[p][cl]);
    }
}

// ---------------- deform sampling of Z (NHWC bf16) + db ---------------------
__global__ __launch_bounds__(256) void deform_kernel(
    const unsigned short* __restrict__ Z,   // (8,3136,256) bf16
    const float* __restrict__ pm,           // (24,2,3136) fp32
    const float* __restrict__ db,
    unsigned short* __restrict__ out)       // (24,3136,256) bf16
{
    int n = blockIdx.y;
    int t = threadIdx.x;
    int pix = blockIdx.x * 8 + (t >> 5);
    int g = t & 31;                  // 8-channel group
    int fi = n / 3;
    int y = pix / 56, x = pix % 56;
    float dy = pm[((size_t)n * 2 + 0) * NPIX + pix];
    float dx = pm[((size_t)n * 2 + 1) * NPIX + pix];
    float gy = (float)y + dy, gx = (float)x + dx;
    float y0f = floorf(gy), x0f = floorf(gx);
    float ty = gy - y0f, tx = gx - x0f;
    int y0 = (int)y0f, x0 = (int)x0f, y1 = y0 + 1, x1 = x0 + 1;
    bool vy0 = (unsigned)y0 < 56u, vy1 = (unsigned)y1 < 56u;
    bool vx0 = (unsigned)x0 < 56u, vx1 = (unsigned)x1 < 56u;
    float w00 = (1.f - ty) * (1.f - tx) * (vy0 && vx0 ? 1.f : 0.f);
    float w01 = (1.f - ty) * tx * (vy0 && vx1 ? 1.f : 0.f);
    float w10 = ty * (1.f - tx) * (vy1 && vx0 ? 1.f : 0.f);
    float w11 = ty * tx * (vy1 && vx1 ? 1.f : 0.f);
    int y0c = vy0 ? y0 : 0, y1c = vy1 ? y1 : 0;
    int x0c = vx0 ? x0 : 0, x1c = vx1 ? x1 : 0;
    const unsigned short* Zf = Z + (size_t)fi * NPIX * 256 + g * 8;
    const unsigned short* p00 = Zf + (size_t)(y0c * 56 + x0c) * 256;
    const unsigned short* p01 = Zf + (size_t)(y0c * 56 + x1c) * 256;
    const unsigned short* p10 = Zf + (size_t)(y1c * 56 + x0c) * 256;
    const unsigned short* p11 = Zf + (size_t)(y1c * 56 + x1c) * 256;
    unsigned short r[8];
#pragma unroll
    for (int j = 0; j < 8; j++) {
        float v = b2f(p00[j]) * w00 + b2f(p01[j]) * w01 +
                  b2f(p10[j]) * w10 + b2f(p11[j]) * w11;
        v += db[g * 8 + j];
        r[j] = f2b(v);
    }
    *(int4*)(out + ((size_t)n * NPIX + pix) * 256 + g * 8) = *(int4*)r;
}

// ---------------- final: p2d = pf+emb -> fp32 NCHW, pooled (scaled atomics) -
__global__ __launch_bounds__(256) void final_kernel(
    const unsigned short* __restrict__ pf, const unsigned short* __restrict__ emb,
    float* __restrict__ dout)
{
    __shared__ float s[64 * 135];
    int n = blockIdx.y;
    int p0 = blockIdx.x * 64;
    int t = threadIdx.x;
    float* p2d = dout + 6144 + (size_t)n * CDIM * NPIX;
    for (int cpass = 0; cpass < 2; cpass++) {
        int cb = cpass * 128;
        int g = t & 15, pq = t >> 4;
#pragma unroll
        for (int ii = 0; ii < 4; ii++) {
            int p = pq + ii * 16;
            size_t base = ((size_t)n * NPIX + p0 + p) * 256 + cb + g * 8;
            int4 a4 = *(const int4*)(pf + base);
            int4 b4 = *(const int4*)(emb + base);
            const unsigned short* au = (const unsigned short*)&a4;
            const unsigned short* bu = (const unsigned short*)&b4;
#pragma unroll
            for (int j = 0; j < 8; j++)
                s[p * 135 + g * 8 + j] = b2f(au[j]) + b2f(bu[j]);
        }
        __syncthreads();
        int p = t & 63, cw = t >> 6;
#pragma unroll
        for (int i = 0; i < 32; i++) {
            int c = cw * 32 + i;
            float v = s[p * 135 + c];
            p2d[(size_t)(cb + c) * NPIX + p0 + p] = v;
            float sum = v;
#pragma unroll
            for (int off = 32; off > 0; off >>= 1) sum += __shfl_down(sum, off, 64);
            if (p == 0) atomicAdd(dout + n * CDIM + cb + c, sum * (1.f / 3136.f));
        }
        __syncthreads();
    }
}

extern "C" void kernel_launch(void* const* d_in, const int* in_sizes, int n_in,
                              void* d_out, int out_size, void* d_ws, size_t ws_size,
                              hipStream_t stream)
{
    const float* i_features = (const float*)d_in[1];
    const float* p_motions  = (const float*)d_in[2];
    const float* dw  = (const float*)d_in[3];
    const float* db  = (const float*)d_in[4];
    const float* mw1 = (const float*)d_in[5];
    const float* mb1 = (const float*)d_in[6];
    const float* mw2 = (const float*)d_in[7];
    const float* mb2 = (const float*)d_in[8];
    const float* mw3 = (const float*)d_in[9];
    const float* mb3 = (const float*)d_in[10];
    const float* ew1 = (const float*)d_in[11];
    const float* eb1 = (const float*)d_in[12];
    const float* ew2 = (const float*)d_in[13];
    const float* eb2 = (const float*)d_in[14];
    const float* ew3 = (const float*)d_in[15];
    const float* eb3 = (const float*)d_in[16];
    const float* ew4 = (const float*)d_in[17];
    const float* eb4 = (const float*)d_in[18];
    float* out = (float*)d_out;

    // workspace layout (bytes)
    char* p = (char*)d_ws;
    float* pm = (float*)p;            p += 602112;
    unsigned short* wpk = (unsigned short*)p;   // 6x 3x3 (contiguous) + 1x1
    unsigned short* wpE2 = wpk + 0 * 589824;
    unsigned short* wpE3 = wpk + 1 * 589824;
    unsigned short* wpE4 = wpk + 2 * 589824;
    unsigned short* wpM1 = wpk + 3 * 589824;
    unsigned short* wpM2 = wpk + 4 * 589824;
    unsigned short* wpM3 = wpk + 5 * 589824;
    unsigned short* wpDW = wpk + 6 * 589824;
    p += (6 * 589824 + 65536) * 2;
    unsigned short* actA = (unsigned short*)p; p += 38535168;
    unsigned short* actB = (unsigned short*)p; p += 38535168;
    unsigned short* embB = (unsigned short*)p; p += 38535168;

    hipMemsetAsync(out, 0, 6144 * sizeof(float), stream);  // pooled accumulators

    resize_pm_kernel<<<(NN * 2 * NPIX + 255) / 256, 256, 0, stream>>>(p_motions, pm);
    pack_all_kernel<<<6 * 2304 + 256, 256, 0, stream>>>(
        ew2, ew3, ew4, mw1, mw2, mw3, dw, wpk);

    // emb chain (bf16 NHWC)
    ew1_kernel<<<dim3(392, NN), 256, 0, stream>>>(pm, ew1, eb1, actA);
    dim3 cg24(7, 4, NN), cg8(7, 4, 8);
    conv_mfma<9, true, true><<<cg24, 256, 0, stream>>>(actA, wpE2, eb2, actB);
    conv_mfma<9, true, true><<<cg24, 256, 0, stream>>>(actB, wpE3, eb3, actA);
    conv_mfma<9, true, true><<<cg24, 256, 0, stream>>>(actA, wpE4, eb4, embB);

    // Z = dw * i_features (on the 8 unique maps), then deform-sample Z (+db)
    transpose_fI<<<dim3(49, 4, 8), 256, 0, stream>>>(i_features, actA);
    conv_mfma<1, false, false><<<cg8, 256, 0, stream>>>(actA, wpDW, nullptr, actB);
    deform_kernel<<<dim3(392, NN), 256, 0, stream>>>(actB, pm, db, actA);

    // pf chain
    conv_mfma<9, true, true><<<cg24, 256, 0, stream>>>(actA, wpM1, mb1, actB);
    conv_mfma<9, true, true><<<cg24, 256, 0, stream>>>(actB, wpM2, mb2, actA);
    conv_mfma<9, true, true><<<cg24, 256, 0, stream>>>(actA, wpM3, mb3, actB);

    // p2d + pooled (scale folded into atomics; d_out head pre-zeroed)
    final_kernel<<<dim3(49, NN), 256, 0, stream>>>(actB, embB, out);
}

// Round 6
// 730.368 us; speedup vs baseline: 2.1310x; 1.1530x over previous
//
#include <hip/hip_runtime.h>

// Shapes: imgs(2,16,3,224,224)[shape only], i_features(8,256,56,56) fp32,
// p_motions(2,12,2,112,112) fp32 -> N=24 frames, C=256, H=W=56, k=3.
#define NPIX 3136
#define NN   24
#define CDIM 256

typedef __attribute__((ext_vector_type(8))) short short8v;   // 8 bf16 (A/B frag)
typedef __attribute__((ext_vector_type(4))) float float4v;   // 4 fp32 (C/D frag)

typedef __attribute__((address_space(1))) const void gvoid;
typedef __attribute__((address_space(3))) void lvoid;
static __device__ __forceinline__ void async_copy16(const void* g, void* l) {
    // lane's 16B lands at l + lane*16 (wave-uniform LDS base)
    __builtin_amdgcn_global_load_lds((gvoid*)g, (lvoid*)l, 16, 0, 0);
}

static __device__ __forceinline__ unsigned short f2b(float f) {
    unsigned int u = __float_as_uint(f);
    u = (u + 0x7FFFu + ((u >> 16) & 1u)) >> 16;   // RNE
    return (unsigned short)u;
}
static __device__ __forceinline__ float b2f(unsigned short h) {
    return __uint_as_float(((unsigned int)h) << 16);
}

// ---------------- resize(112->56)*scale == avg2x2 * 0.0625 ------------------
__global__ __launch_bounds__(256) void resize_pm_kernel(
    const float* __restrict__ pmo, float* __restrict__ pm)
{
    int idx = blockIdx.x * 256 + threadIdx.x;
    if (idx >= NN * 2 * NPIX) return;
    int x = idx % 56, y = (idx / 56) % 56, nc = idx / NPIX;
    const float* src = pmo + (size_t)nc * 112 * 112 + (size_t)(2 * y) * 112 + 2 * x;
    pm[idx] = (src[0] + src[1] + src[112] + src[113]) * 0.0625f;
}

// ---------------- merged weight packing (6x 3x3 + 1x 1x1) -------------------
// 3x3: dst [cb4][ch8][tap9][g4][lane64][8]; co=cb*64+g*16+(lane&15),
//      ci=ch*32+(lane>>4)*8+j. 1x1 same without tap. dsts contiguous in ws.
__global__ __launch_bounds__(256) void pack_all_kernel(
    const float* __restrict__ s0, const float* __restrict__ s1,
    const float* __restrict__ s2, const float* __restrict__ s3,
    const float* __restrict__ s4, const float* __restrict__ s5,
    const float* __restrict__ sdw, unsigned short* __restrict__ dstbase)
{
    int bx = blockIdx.x;
    if (bx < 6 * 2304) {
        int wi = bx / 2304;
        int d = (bx % 2304) * 256 + threadIdx.x;
        const float* w = (wi == 0) ? s0 : (wi == 1) ? s1 : (wi == 2) ? s2
                       : (wi == 3) ? s3 : (wi == 4) ? s4 : s5;
        int j = d & 7;
        int lane = (d >> 3) & 63;
        int g = (d >> 9) & 3;
        int e = d >> 11;
        int tap = e % 9;
        int f = e / 9;
        int ch = f & 7, cb = f >> 3;
        int co = cb * 64 + g * 16 + (lane & 15);
        int ci = ch * 32 + (lane >> 4) * 8 + j;
        dstbase[(size_t)wi * 589824 + d] = f2b(w[((size_t)co * 256 + ci) * 9 + tap]);
    } else {
        int d = (bx - 6 * 2304) * 256 + threadIdx.x;
        int j = d & 7;
        int lane = (d >> 3) & 63;
        int g = (d >> 9) & 3;
        int ch = (d >> 11) & 7;
        int cb = d >> 14;
        int co = cb * 64 + g * 16 + (lane & 15);
        int ci = ch * 32 + (lane >> 4) * 8 + j;
        dstbase[(size_t)6 * 589824 + d] = f2b(sdw[(size_t)co * 256 + ci]);
    }
}

// ---------------- ew1 conv (Cin=2, K=18) fp32 direct -> bf16 NHWC + relu ----
__global__ __launch_bounds__(256) void ew1_kernel(
    const float* __restrict__ pm, const float* __restrict__ w,   // (256,2,3,3)
    const float* __restrict__ b, unsigned short* __restrict__ out)
{
    __shared__ float sT[8][18];
    __shared__ float sW1[256 * 19];
    int n = blockIdx.y;
    int pixbase = blockIdx.x * 8;
    int t = threadIdx.x;
    if (t < 144) {
        int p = t / 18, j = t % 18;
        int ci = j / 9, tap = j % 9;
        int pix = pixbase + p;
        int y = pix / 56, x = pix % 56;
        int yy = y + tap / 3 - 1, xx = x + tap % 3 - 1;
        float v = 0.f;
        if ((unsigned)yy < 56u && (unsigned)xx < 56u)
            v = pm[((size_t)n * 2 + ci) * NPIX + yy * 56 + xx];
        sT[p][j] = v;
    }
    for (int idx = t; idx < 4608; idx += 256) {
        int co = idx / 18, j = idx % 18;
        sW1[co * 19 + j] = w[idx];
    }
    __syncthreads();
    int co = t;
    float bias = b[co];
#pragma unroll
    for (int p = 0; p < 8; p++) {
        float acc = bias;
#pragma unroll
        for (int j = 0; j < 18; j++) acc += sT[p][j] * sW1[co * 19 + j];
        acc = fmaxf(acc, 0.f);
        out[((size_t)n * NPIX + pixbase + p) * 256 + co] = f2b(acc);
    }
}

// ---------------- MFMA implicit-GEMM conv (NHWC bf16 -> NHWC bf16) ----------
// Row-flattened tile: 64 cout x 448 px = 8 FULL rows. 4 waves each 64co x
// 112px (4x7 acc). Grid-x padded to 8 (bx==7 exits) so the 4 cb-duplicates
// of a row stripe are 8 block-ids apart -> same XCD (id%8) -> L2-resident
// input re-reads. FUSE path: p2d = relu(acc+bias)+emb -> fp32 NCHW + pooled
// atomics (replaces final_kernel).
template <int TAPS, bool RELU, bool HASB, bool FUSE>
__global__ __launch_bounds__(256, 2) void conv_mfma(
    const unsigned short* __restrict__ in,   // (NI,3136,256) bf16
    const unsigned short* __restrict__ wp,   // [4][8][TAPS][4][64][8] bf16
    const float* __restrict__ bias,
    unsigned short* __restrict__ out,        // bf16 NHWC (non-FUSE)
    const unsigned short* __restrict__ emb,  // (FUSE) bf16 NHWC
    float* __restrict__ dout)                // (FUSE) pooled[6144] + p2d fp32 NCHW
{
    constexpr int W_ITERS = TAPS * 4;                       // 36 / 4
    constexpr int SIN_SHORTS = (TAPS == 9) ? 10 * 58 * 32 : 448 * 32;

    __shared__ unsigned short sIn[SIN_SHORTS];
    __shared__ unsigned short sW[W_ITERS * 512];

    const int r0 = blockIdx.x * 8;     // row base; bx==7 is an XCD-pad dummy
    if (r0 >= 56) return;
    const int tid = threadIdx.x;
    const int lane = tid & 63;
    const int wv = tid >> 6;
    const int col = lane & 15;
    const int quad = lane >> 4;
    const int cb = blockIdx.y;         // 64-cout block
    const int n = blockIdx.z;

    const unsigned short* inN = in + (size_t)n * NPIX * 256;
    const unsigned short* wcb = wp + (size_t)cb * 8 * W_ITERS * 512;

    // per-lane B-frag row offsets (y*58 + x for 3x3; flat px for 1x1)
    int rowoff[7];
#pragma unroll
    for (int nj = 0; nj < 7; nj++) {
        int pxl = wv * 112 + nj * 16 + col;
        if (TAPS == 9) {
            int yl = pxl / 56;
            rowoff[nj] = yl * 58 + (pxl - yl * 56);
        } else {
            rowoff[nj] = pxl;
        }
    }
    const int qoff = quad * 8;
    // per-lane global staging offset within a 16px x 32ci slab
    const int laneSrc = (lane >> 2) * 256 + (lane & 3) * 8;

    if (TAPS == 9) {
        // prezero: x-border pads + out-of-image halo rows stay 0 all chunks
        for (int i = tid * 8; i < SIN_SHORTS; i += 2048)
            *(int4*)(sIn + i) = (int4){0, 0, 0, 0};
    }

    float4v acc[4][7];
#pragma unroll
    for (int mi = 0; mi < 4; mi++)
#pragma unroll
        for (int nj = 0; nj < 7; nj++) acc[mi][nj] = (float4v){0.f, 0.f, 0.f, 0.f};

    for (int ch = 0; ch < 8; ch++) {
        const int c0 = ch * 32;
        __syncthreads();   // prev compute done (first pass: prezero visible)
        // stage weights: contiguous 1KB per wave-iter
        const unsigned short* wchunk = wcb + (size_t)ch * W_ITERS * 512;
#pragma unroll
        for (int it = wv; it < W_ITERS; it += 4)
            async_copy16(wchunk + it * 512 + lane * 8, sW + it * 512);
        // stage input
        if (TAPS == 9) {
#pragma unroll
            for (int ry = 0; ry < 10; ry++) {
                int k = (wv - ry) & 3;          // all (ry,k) covered, balanced
                int gy = r0 + ry - 1;
                if ((unsigned)gy < 56u && (k < 3 || lane < 32))
                    async_copy16(inN + (size_t)gy * 14336 + k * 4096 + c0 + laneSrc,
                                 sIn + ry * 1856 + 32 + k * 512);
            }
        } else {
#pragma unroll
            for (int k = 0; k < 7; k++) {
                int it = wv + k * 4;
                async_copy16(inN + (size_t)r0 * 14336 + it * 4096 + c0 + laneSrc,
                             sIn + it * 512);
            }
        }
        __syncthreads();   // drain + visibility
#pragma unroll
        for (int tap = 0; tap < TAPS; tap++) {
            const int coff = (TAPS == 9) ? ((tap / 3) * 58 + (tap % 3)) * 32 : 0;
            short8v a[4], b[7];
#pragma unroll
            for (int mi = 0; mi < 4; mi++)
                a[mi] = *(const short8v*)(sW + ((tap * 4 + mi) * 64 + lane) * 8);
#pragma unroll
            for (int nj = 0; nj < 7; nj++)
                b[nj] = *(const short8v*)(sIn + rowoff[nj] * 32 + coff + qoff);
#pragma unroll
            for (int mi = 0; mi < 4; mi++)
#pragma unroll
                for (int nj = 0; nj < 7; nj++)
                    acc[mi][nj] = __builtin_amdgcn_mfma_f32_16x16x32_bf16(
                        a[mi], b[nj], acc[mi][nj], 0, 0, 0);
        }
    }

    if (!FUSE) {
        // epilogue: D row = quad*4+reg (cout), col = pixel; no masks
        unsigned short* outT = out + ((size_t)n * NPIX + r0 * 56 + wv * 112) * 256 + cb * 64;
#pragma unroll
        for (int mi = 0; mi < 4; mi++) {
            float4v bv = (float4v){0.f, 0.f, 0.f, 0.f};
            if (HASB) bv = *(const float4v*)(bias + cb * 64 + mi * 16 + quad * 4);
#pragma unroll
            for (int nj = 0; nj < 7; nj++) {
                float v0 = acc[mi][nj][0] + bv[0];
                float v1 = acc[mi][nj][1] + bv[1];
                float v2 = acc[mi][nj][2] + bv[2];
                float v3 = acc[mi][nj][3] + bv[3];
                if (RELU) {
                    v0 = fmaxf(v0, 0.f); v1 = fmaxf(v1, 0.f);
                    v2 = fmaxf(v2, 0.f); v3 = fmaxf(v3, 0.f);
                }
                uint2 pk;
                pk.x = (unsigned)f2b(v0) | ((unsigned)f2b(v1) << 16);
                pk.y = (unsigned)f2b(v2) | ((unsigned)f2b(v3) << 16);
                *(uint2*)(outT + ((size_t)(nj * 16 + col)) * 256 + mi * 16 + quad * 4) = pk;
            }
        }
    } else {
        // fused final: p2d = relu(acc+bias) + emb -> fp32 NCHW; pooled atomics
        const int pixBase = r0 * 56 + wv * 112;
        float* p2d = dout + 6144 + (size_t)n * CDIM * NPIX;
        float sums[4][4];
#pragma unroll
        for (int mi = 0; mi < 4; mi++)
#pragma unroll
            for (int q = 0; q < 4; q++) sums[mi][q] = 0.f;
#pragma unroll
        for (int mi = 0; mi < 4; mi++) {
            float4v bv = *(const float4v*)(bias + cb * 64 + mi * 16 + quad * 4);
            const int co0 = cb * 64 + mi * 16 + quad * 4;
#pragma unroll
            for (int nj = 0; nj < 7; nj++) {
                int pix = pixBase + nj * 16 + col;
                uint2 e = *(const uint2*)(emb + ((size_t)n * NPIX + pix) * 256 + co0);
                float v0 = fmaxf(acc[mi][nj][0] + bv[0], 0.f) + b2f((unsigned short)(e.x & 0xFFFF));
                float v1 = fmaxf(acc[mi][nj][1] + bv[1], 0.f) + b2f((unsigned short)(e.x >> 16));
                float v2 = fmaxf(acc[mi][nj][2] + bv[2], 0.f) + b2f((unsigned short)(e.y & 0xFFFF));
                float v3 = fmaxf(acc[mi][nj][3] + bv[3], 0.f) + b2f((unsigned short)(e.y >> 16));
                p2d[(size_t)(co0 + 0) * NPIX + pix] = v0;
                p2d[(size_t)(co0 + 1) * NPIX + pix] = v1;
                p2d[(size_t)(co0 + 2) * NPIX + pix] = v2;
                p2d[(size_t)(co0 + 3) * NPIX + pix] = v3;
                sums[mi][0] += v0; sums[mi][1] += v1;
                sums[mi][2] += v2; sums[mi][3] += v3;
            }
        }
        // reduce each sum over the 16 lanes of the quad; col==0 lane commits
#pragma unroll
        for (int mi = 0; mi < 4; mi++)
#pragma unroll
            for (int q = 0; q < 4; q++) {
                float s = sums[mi][q];
                s += __shfl_down(s, 8, 16);
                s += __shfl_down(s, 4, 16);
                s += __shfl_down(s, 2, 16);
                s += __shfl_down(s, 1, 16);
                if (col == 0)
                    atomicAdd(dout + n * CDIM + cb * 64 + mi * 16 + quad * 4 + q,
                              s * (1.f / 3136.f));
            }
    }
}

// ---------------- i_features NCHW fp32 -> NHWC bf16 -------------------------
__global__ __launch_bounds__(256) void transpose_fI(
    const float* __restrict__ feat, unsigned short* __restrict__ dst)
{
    __shared__ float s[64][65];
    int fi = blockIdx.z;
    int p0 = blockIdx.x * 64;
    int c0 = blockIdx.y * 64;
    int t = threadIdx.x;
    int pl = t & 63, cq = t >> 6;
#pragma unroll
    for (int i = 0; i < 16; i++) {
        int c = cq + i * 4;
        s[pl][c] = feat[((size_t)fi * 256 + c0 + c) * NPIX + p0 + pl];
    }
    __syncthreads();
    int cl = t & 63, pq = t >> 6;
#pragma unroll
    for (int i = 0; i < 16; i++) {
        int p = pq + i * 4;
        dst[((size_t)fi * NPIX + p0 + p) * 256 + c0 + cl] = f2b(s[p][cl]);
    }
}

// ---------------- deform sampling of Z (NHWC bf16) + db ---------------------
__global__ __launch_bounds__(256) void deform_kernel(
    const unsigned short* __restrict__ Z,   // (8,3136,256) bf16
    const float* __restrict__ pm,           // (24,2,3136) fp32
    const float* __restrict__ db,
    unsigned short* __restrict__ out)       // (24,3136,256) bf16
{
    int n = blockIdx.y;
    int t = threadIdx.x;
    int pix = blockIdx.x * 8 + (t >> 5);
    int g = t & 31;                  // 8-channel group
    int fi = n / 3;
    int y = pix / 56, x = pix % 56;
    float dy = pm[((size_t)n * 2 + 0) * NPIX + pix];
    float dx = pm[((size_t)n * 2 + 1) * NPIX + pix];
    float gy = (float)y + dy, gx = (float)x + dx;
    float y0f = floorf(gy), x0f = floorf(gx);
    float ty = gy - y0f, tx = gx - x0f;
    int y0 = (int)y0f, x0 = (int)x0f, y1 = y0 + 1, x1 = x0 + 1;
    bool vy0 = (unsigned)y0 < 56u, vy1 = (unsigned)y1 < 56u;
    bool vx0 = (unsigned)x0 < 56u, vx1 = (unsigned)x1 < 56u;
    float w00 = (1.f - ty) * (1.f - tx) * (vy0 && vx0 ? 1.f : 0.f);
    float w01 = (1.f - ty) * tx * (vy0 && vx1 ? 1.f : 0.f);
    float w10 = ty * (1.f - tx) * (vy1 && vx0 ? 1.f : 0.f);
    float w11 = ty * tx * (vy1 && vx1 ? 1.f : 0.f);
    int y0c = vy0 ? y0 : 0, y1c = vy1 ? y1 : 0;
    int x0c = vx0 ? x0 : 0, x1c = vx1 ? x1 : 0;
    const unsigned short* Zf = Z + (size_t)fi * NPIX * 256 + g * 8;
    const unsigned short* p00 = Zf + (size_t)(y0c * 56 + x0c) * 256;
    const unsigned short* p01 = Zf + (size_t)(y0c * 56 + x1c) * 256;
    const unsigned short* p10 = Zf + (size_t)(y1c * 56 + x0c) * 256;
    const unsigned short* p11 = Zf + (size_t)(y1c * 56 + x1c) * 256;
    unsigned short r[8];
#pragma unroll
    for (int j = 0; j < 8; j++) {
        float v = b2f(p00[j]) * w00 + b2f(p01[j]) * w01 +
                  b2f(p10[j]) * w10 + b2f(p11[j]) * w11;
        v += db[g * 8 + j];
        r[j] = f2b(v);
    }
    *(int4*)(out + ((size_t)n * NPIX + pix) * 256 + g * 8) = *(int4*)r;
}

extern "C" void kernel_launch(void* const* d_in, const int* in_sizes, int n_in,
                              void* d_out, int out_size, void* d_ws, size_t ws_size,
                              hipStream_t stream)
{
    const float* i_features = (const float*)d_in[1];
    const float* p_motions  = (const float*)d_in[2];
    const float* dw  = (const float*)d_in[3];
    const float* db  = (const float*)d_in[4];
    const float* mw1 = (const float*)d_in[5];
    const float* mb1 = (const float*)d_in[6];
    const float* mw2 = (const float*)d_in[7];
    const float* mb2 = (const float*)d_in[8];
    const float* mw3 = (const float*)d_in[9];
    const float* mb3 = (const float*)d_in[10];
    const float* ew1 = (const float*)d_in[11];
    const float* eb1 = (const float*)d_in[12];
    const float* ew2 = (const float*)d_in[13];
    const float* eb2 = (const float*)d_in[14];
    const float* ew3 = (const float*)d_in[15];
    const float* eb3 = (const float*)d_in[16];
    const float* ew4 = (const float*)d_in[17];
    const float* eb4 = (const float*)d_in[18];
    float* out = (float*)d_out;

    // workspace layout (bytes)
    char* p = (char*)d_ws;
    float* pm = (float*)p;            p += 602112;
    unsigned short* wpk = (unsigned short*)p;   // 6x 3x3 (contiguous) + 1x1
    unsigned short* wpE2 = wpk + 0 * 589824;
    unsigned short* wpE3 = wpk + 1 * 589824;
    unsigned short* wpE4 = wpk + 2 * 589824;
    unsigned short* wpM1 = wpk + 3 * 589824;
    unsigned short* wpM2 = wpk + 4 * 589824;
    unsigned short* wpM3 = wpk + 5 * 589824;
    unsigned short* wpDW = wpk + 6 * 589824;
    p += (6 * 589824 + 65536) * 2;
    unsigned short* actA = (unsigned short*)p; p += 38535168;
    unsigned short* actB = (unsigned short*)p; p += 38535168;
    unsigned short* embB = (unsigned short*)p; p += 38535168;

    hipMemsetAsync(out, 0, 6144 * sizeof(float), stream);  // pooled accumulators

    resize_pm_kernel<<<(NN * 2 * NPIX + 255) / 256, 256, 0, stream>>>(p_motions, pm);
    pack_all_kernel<<<6 * 2304 + 256, 256, 0, stream>>>(
        ew2, ew3, ew4, mw1, mw2, mw3, dw, wpk);

    // emb chain (bf16 NHWC)
    ew1_kernel<<<dim3(392, NN), 256, 0, stream>>>(pm, ew1, eb1, actA);
    dim3 cg24(8, 4, NN), cg8(8, 4, 8);   // x padded to 8 for XCD congruence
    conv_mfma<9, true, true, false><<<cg24, 256, 0, stream>>>(actA, wpE2, eb2, actB, nullptr, nullptr);
    conv_mfma<9, true, true, false><<<cg24, 256, 0, stream>>>(actB, wpE3, eb3, actA, nullptr, nullptr);
    conv_mfma<9, true, true, false><<<cg24, 256, 0, stream>>>(actA, wpE4, eb4, embB, nullptr, nullptr);

    // Z = dw * i_features (on the 8 unique maps), then deform-sample Z (+db)
    transpose_fI<<<dim3(49, 4, 8), 256, 0, stream>>>(i_features, actA);
    conv_mfma<1, false, false, false><<<cg8, 256, 0, stream>>>(actA, wpDW, nullptr, actB, nullptr, nullptr);
    deform_kernel<<<dim3(392, NN), 256, 0, stream>>>(actB, pm, db, actA);

    // pf chain; last conv fuses p2d assembly + pooled reduction
    conv_mfma<9, true, true, false><<<cg24, 256, 0, stream>>>(actA, wpM1, mb1, actB, nullptr, nullptr);
    conv_mfma<9, true, true, false><<<cg24, 256, 0, stream>>>(actB, wpM2, mb2, actA, nullptr, nullptr);
    conv_mfma<9, true, true, true><<<cg24, 256, 0, stream>>>(actA, wpM3, mb3, nullptr, embB, out);
}